// Round 6
// baseline (136.915 us; speedup 1.0000x reference)
//
#include <hip/hip_runtime.h>
#include <math.h>

#define B_ 32
#define D_ 16
#define T_ 1024
#define P_ 64
#define L_ 32
#define KB 524288.0f       // 2^19 bias: prefmin(e) = KB - prefmax(KB - e)

typedef short short8 __attribute__((ext_vector_type(8)));
typedef float f32x4 __attribute__((ext_vector_type(4)));
typedef unsigned short ushort_t;

// ---- DPP helpers -----------------------------------------------------------
template<int CTRL, int ROW_MASK, bool BC>
__device__ __forceinline__ float dpp_mov(float old_, float src) {
  int o = __builtin_bit_cast(int, old_);
  int s = __builtin_bit_cast(int, src);
  int r = __builtin_amdgcn_update_dpp(o, s, CTRL, ROW_MASK, 0xf, BC);
  return __builtin_bit_cast(float, r);
}

// Inclusive prefix-sum over each 32-lane half (0-fill -> fused v_add_f32_dpp).
__device__ __forceinline__ float scan_sum32(float v) {
  v += dpp_mov<0x111, 0xf, true>(0.f, v);   // row_shr:1
  v += dpp_mov<0x112, 0xf, true>(0.f, v);   // row_shr:2
  v += dpp_mov<0x114, 0xf, true>(0.f, v);   // row_shr:4
  v += dpp_mov<0x118, 0xf, true>(0.f, v);   // row_shr:8
  v += dpp_mov<0x142, 0xa, false>(0.f, v);  // row_bcast15 -> rows 1,3
  return v;
}

// DUAL inclusive prefix-MAX over each 32-lane half: two independent chains
// interleaved in one asm block. Chain B's dpp fills chain A's 2-wait-state
// VALU->DPP hazard window; measured marginal cost of the 2nd chain = +31cyc
// (R4: lambda_pair 321 vs lambda_col 290).
__device__ __forceinline__ void scan_max32_x2(float& u, float& v) {
  asm("s_nop 1\n\t"
      "v_max_f32_dpp %0, %0, %0 row_shr:1 row_mask:0xf bank_mask:0xf\n\t"
      "v_max_f32_dpp %1, %1, %1 row_shr:1 row_mask:0xf bank_mask:0xf\n\t"
      "s_nop 0\n\t"
      "v_max_f32_dpp %0, %0, %0 row_shr:2 row_mask:0xf bank_mask:0xf\n\t"
      "v_max_f32_dpp %1, %1, %1 row_shr:2 row_mask:0xf bank_mask:0xf\n\t"
      "s_nop 0\n\t"
      "v_max_f32_dpp %0, %0, %0 row_shr:4 row_mask:0xf bank_mask:0xf\n\t"
      "v_max_f32_dpp %1, %1, %1 row_shr:4 row_mask:0xf bank_mask:0xf\n\t"
      "s_nop 0\n\t"
      "v_max_f32_dpp %0, %0, %0 row_shr:8 row_mask:0xf bank_mask:0xf\n\t"
      "v_max_f32_dpp %1, %1, %1 row_shr:8 row_mask:0xf bank_mask:0xf\n\t"
      "s_nop 0\n\t"
      "v_max_f32_dpp %0, %0, %0 row_bcast:15 row_mask:0xa bank_mask:0xf\n\t"
      "v_max_f32_dpp %1, %1, %1 row_bcast:15 row_mask:0xa bank_mask:0xf"
      : "+v"(u), "+v"(v));
}

__device__ __forceinline__ ushort_t f2bf(float f) {   // fp32 -> bf16 RNE
  unsigned u = __builtin_bit_cast(unsigned, f);
  return (ushort_t)((u + 0x7FFFu + ((u >> 16) & 1u)) >> 16);
}
__device__ __forceinline__ float bf2f(ushort_t h) {
  unsigned u = ((unsigned)h) << 16;
  return __builtin_bit_cast(float, u);
}

// ---- fused prep: blocks 0..127 do prep_x, blocks 128..143 do prep_patt x4 --
__global__ __launch_bounds__(256) void prep_fused(
    const float* __restrict__ x, const float* __restrict__ patts,
    ushort_t* __restrict__ xA, ushort_t* __restrict__ pB) {
  const int bid = blockIdx.x;
  if (bid < 128) {
    int gid = bid * 256 + threadIdx.x;      // < 32768 = B_*T_
    int b = gid >> 10, t = gid & 1023;
    float x2 = 0.f;
    ushort_t o[32];
#pragma unroll
    for (int d = 0; d < 16; ++d) {
      float v = x[((b * 16 + d) << 10) + t];   // coalesced over t
      x2 = fmaf(v, v, x2);
      o[d] = f2bf(v);
    }
    o[16] = 0x3F80; o[17] = 0x3F80;            // bf16(1.0)
    ushort_t hi = f2bf(x2);
    o[18] = hi;
    o[19] = f2bf(x2 - bf2f(hi));               // hi/lo split
#pragma unroll
    for (int d = 20; d < 32; ++d) o[d] = 0;
    uint4* dst = (uint4*)(xA + (size_t)gid * 32);
#pragma unroll
    for (int q = 0; q < 4; ++q) {
      const ushort_t* s = o + q * 8;
      uint4 u;
      u.x = (unsigned)s[0] | ((unsigned)s[1] << 16);
      u.y = (unsigned)s[2] | ((unsigned)s[3] << 16);
      u.z = (unsigned)s[4] | ((unsigned)s[5] << 16);
      u.w = (unsigned)s[6] | ((unsigned)s[7] << 16);
      dst[q] = u;
    }
  } else {
    __shared__ float Ls[4][16 * 33];
    __shared__ float Lh[4][64];
    __shared__ float LP2[4][32];
    const int sub = threadIdx.x >> 6;
    const int l = threadIdx.x & 63;
    const int p = (bid - 128) * 4 + sub;
    const int half = l >> 5;
    const int m = l & 31;

    float p2acc = 0.f;
#pragma unroll
    for (int dd = 0; dd < 16; dd += 2) {
      int d = dd + half;                       // half 0: even d, half 1: odd d
      float v = patts[((p * 16 + d) << 5) + m];
      p2acc = fmaf(v, v, p2acc);
      Ls[sub][d * 33 + m] = scan_sum32(v);     // prefix over m (per half)
    }
    Lh[sub][l] = p2acc;
    __syncthreads();
    {
      float tot = Lh[sub][m] + Lh[sub][32 + m];
      float pref = scan_sum32(tot);
      if (half == 0) LP2[sub][m] = pref;
    }
    __syncthreads();

    const int n = l & 15, q = l >> 4;
#pragma unroll
    for (int iblk = 0; iblk < 2; ++iblk) {
      const int i = iblk * 16 + n;
      ushort_t o[8];
      if (q < 2) {
#pragma unroll
        for (int e = 0; e < 8; ++e)
          o[e] = f2bf(-2.f * Ls[sub][(q * 8 + e) * 33 + i]);
      } else if (q == 2) {
        float P2 = LP2[sub][i];
        ushort_t hi = f2bf(P2);
        o[0] = hi; o[1] = f2bf(P2 - bf2f(hi));
        o[2] = f2bf((float)(i + 1)); o[3] = o[2];
        o[4] = o[5] = o[6] = o[7] = 0;
      } else {
#pragma unroll
        for (int e = 0; e < 8; ++e) o[e] = 0;
      }
      uint4 u;
      u.x = (unsigned)o[0] | ((unsigned)o[1] << 16);
      u.y = (unsigned)o[2] | ((unsigned)o[3] << 16);
      u.z = (unsigned)o[4] | ((unsigned)o[5] << 16);
      u.w = (unsigned)o[6] | ((unsigned)o[7] << 16);
      ((uint4*)pB)[(p * 2 + iblk) * 64 + l] = u;
    }
  }
}

// ---- main kernel -----------------------------------------------------------
// R6: dual-chain + C=8, derived from the consolidated R1-R5 model:
//   wall = max(cols/chain * lambda_k, issue-bound). lambda_pair = 321 cyc
//   (R4 measured: 2nd in-wave chain costs +31 cyc, hides in the 1st's
//   dependency stalls). Minimize cols/chain: C=8 chunks -> X=22 tiles/chain
//   (PERFECTLY uniform: ch0 stores 22, ch>=1 warm 16 + store 6; S0=6*ch).
//   Predicted wall = 352 col-pairs * ~321 = 113k cyc ~ 47us (R3: 130k).
//  * Each wave: 2 independent dual-pattern DP chains (4 patterns), shared
//    A-fragment, instruction-interleaved (R4's verified arithmetic).
//  * No pad rows (fits 4 blocks/CU at exactly 160KB): Zx row-0 = KB via
//    clamped row address + 1 cndmask per col per chain (bit-identical).
//  * Single LDS buffer (reads-before-writes, in-order DS; R3-verified).
__global__ __launch_bounds__(256, 4) void dtw_kernel(
    const ushort_t* __restrict__ xA,    // [B][T][32 bf16]
    const ushort_t* __restrict__ pBg,   // [P][2][64][8 bf16]
    const float* __restrict__ wp,
    float* __restrict__ out)            // [B][P][T]
{
  __shared__ float lds[4 * 2560];   // 4 waves * 2 problems * 2 pat * 32*20 fl

  const int tid = threadIdx.x;
  const int l   = tid & 63;
  const int wid = tid >> 6;
  const int li  = l & 31;
  const int g   = l >> 5;
  const int q4  = l >> 4;
  const unsigned bx = blockIdx.x;
  const int ch   = bx & 7u;                // chunk 0..7
  const unsigned rest = bx >> 3;           // [0,128)
  const int b     = rest >> 2;             // [0,32)
  const int pbase = (rest & 3) << 4;       // 16 patterns per block
  const int pA0   = pbase + (wid << 2);    // this wave: patterns pA0..pA0+3
  const float w = wp[0];
  const float nw = -w;
  const bool l0c = (li == 0), l31 = (li == 31);

  // uniform chunks: S0 = 6*ch, 22 tiles each, ch>0 warm 16 tiles (256 cols)
  const int S0    = 6 * ch;
  const int nT    = 22;
  const int warmT = ch ? 16 : 0;

  // B fragments: 2 problems x 2 patterns x 2 iblks (register-resident)
  const short8* pBs = (const short8*)pBg;
  short8 B00 = pBs[((pA0    ) * 2 + 0) * 64 + l];
  short8 B01 = pBs[((pA0    ) * 2 + 1) * 64 + l];
  short8 B10 = pBs[((pA0 + 1) * 2 + 0) * 64 + l];
  short8 B11 = pBs[((pA0 + 1) * 2 + 1) * 64 + l];
  short8 B20 = pBs[((pA0 + 2) * 2 + 0) * 64 + l];
  short8 B21 = pBs[((pA0 + 2) * 2 + 1) * 64 + l];
  short8 B30 = pBs[((pA0 + 3) * 2 + 0) * 64 + l];
  short8 B31 = pBs[((pA0 + 3) * 2 + 1) * 64 + l];

  const short8* xAs = (const short8*)xA + ((size_t)b << 12);

  short8 Aa;
  auto loadA = [&](int t) {   // t local; global tile = S0 + t; SHARED by A&B
    Aa = xAs[((((S0 + t) << 4) + (l & 15)) << 2) + q4];
  };

  // layout per wave (no pads): probA [pat0 640][pat1 640], probB same +1280
  float* base = lds + wid * 2560;
  float* ldsW = base + (l & 15) * 20 + q4 * 4;
  const int rxrow = (li > 0) ? (li - 1) : 0;           // clamped row address
  const float* ldsRA  = base + g * 640 + li * 20;      // problem A, Z row li
  const float* ldsRxA = base + g * 640 + rxrow * 20;   // row li-1 (li0: own)
  const float* ldsRB  = ldsRA + 1280;                  // problem B
  const float* ldsRxB = ldsRxA + 1280;

  const f32x4 zk = {KB, KB, KB, KB};    // MFMA C operand: Z = S + KB

  auto fill = [&]() {
    f32x4 d0 = __builtin_amdgcn_mfma_f32_16x16x32_bf16(Aa, B00, zk, 0, 0, 0);
    f32x4 d1 = __builtin_amdgcn_mfma_f32_16x16x32_bf16(Aa, B01, zk, 0, 0, 0);
    f32x4 d2 = __builtin_amdgcn_mfma_f32_16x16x32_bf16(Aa, B10, zk, 0, 0, 0);
    f32x4 d3 = __builtin_amdgcn_mfma_f32_16x16x32_bf16(Aa, B11, zk, 0, 0, 0);
    f32x4 d4 = __builtin_amdgcn_mfma_f32_16x16x32_bf16(Aa, B20, zk, 0, 0, 0);
    f32x4 d5 = __builtin_amdgcn_mfma_f32_16x16x32_bf16(Aa, B21, zk, 0, 0, 0);
    f32x4 d6 = __builtin_amdgcn_mfma_f32_16x16x32_bf16(Aa, B30, zk, 0, 0, 0);
    f32x4 d7 = __builtin_amdgcn_mfma_f32_16x16x32_bf16(Aa, B31, zk, 0, 0, 0);
    *(f32x4*)(ldsW + 0)    = d0;      // A pat0, i 0..15   ([i][j] stride 20)
    *(f32x4*)(ldsW + 320)  = d1;      // A pat0, i 16..31
    *(f32x4*)(ldsW + 640)  = d2;      // A pat1, i 0..15
    *(f32x4*)(ldsW + 960)  = d3;      // A pat1, i 16..31
    *(f32x4*)(ldsW + 1280) = d4;      // B pat0, i 0..15
    *(f32x4*)(ldsW + 1600) = d5;      // B pat0, i 16..31
    *(f32x4*)(ldsW + 1920) = d6;      // B pat1, i 0..15
    *(f32x4*)(ldsW + 2240) = d7;      // B pat1, i 16..31
  };

  float* orowA = out + (((size_t)(b * P_ + pA0 + g)) << 10) + (S0 << 4);
  float* orowB = orowA + (2 << 10);
  float dcurA = 0.f, dcurB = 0.f;

  loadA(0);
  fill();
  loadA(1);

  for (int t = 0; t < nT; ++t) {
    // --- DP reads for tile t (both problems), BEFORE fill(t+1) overwrites ---
    f32x4 sA0 = *(const f32x4*)(ldsRA  + 0);
    f32x4 xA0 = *(const f32x4*)(ldsRxA + 0);
    f32x4 sB0 = *(const f32x4*)(ldsRB  + 0);
    f32x4 xB0 = *(const f32x4*)(ldsRxB + 0);
    f32x4 sA1 = *(const f32x4*)(ldsRA  + 4);
    f32x4 xA1 = *(const f32x4*)(ldsRxA + 4);
    f32x4 sB1 = *(const f32x4*)(ldsRB  + 4);
    f32x4 xB1 = *(const f32x4*)(ldsRxB + 4);
    f32x4 sA2 = *(const f32x4*)(ldsRA  + 8);
    f32x4 xA2 = *(const f32x4*)(ldsRxA + 8);
    f32x4 sB2 = *(const f32x4*)(ldsRB  + 8);
    f32x4 xB2 = *(const f32x4*)(ldsRxB + 8);
    f32x4 sA3 = *(const f32x4*)(ldsRA  + 12);
    f32x4 xA3 = *(const f32x4*)(ldsRxA + 12);
    f32x4 sB3 = *(const f32x4*)(ldsRB  + 12);
    f32x4 xB3 = *(const f32x4*)(ldsRxB + 12);

    if (t + 1 < nT) fill();         // consumes Aa = frag(t+1), in-place
    if (t + 2 < nT) loadA(t + 2);

    const bool first = (t == 0);
    const bool store = (t >= warmT);

    float4 rA0, rA1, rA2, rA3, rB0, rB1, rB2, rB3;
#pragma unroll
    for (int k4 = 0; k4 < 4; ++k4) {
      f32x4 SqA = (k4 == 0) ? sA0 : (k4 == 1) ? sA1 : (k4 == 2) ? sA2 : sA3;
      f32x4 XqA = (k4 == 0) ? xA0 : (k4 == 1) ? xA1 : (k4 == 2) ? xA2 : xA3;
      f32x4 SqB = (k4 == 0) ? sB0 : (k4 == 1) ? sB1 : (k4 == 2) ? sB2 : sB3;
      f32x4 XqB = (k4 == 0) ? xB0 : (k4 == 1) ? xB1 : (k4 == 2) ? xB2 : xB3;
      float4 rvA, rvB;
#pragma unroll
      for (int e = 0; e < 4; ++e) {
        float ZoA = SqA[e], ZoB = SqB[e];
        float ZxA = l0c ? KB : XqA[e];          // row -1 = KB (was pad row)
        float ZxB = l0c ? KB : XqB[e];
        float aA = fmaf(nw, dcurA, ZxA);        // ZxA - w*dA
        float cA = fmaf(nw, dcurA, ZoA);        // ZA  - w*dA
        float aB = fmaf(nw, dcurB, ZxB);
        float cB = fmaf(nw, dcurB, ZoB);
        float uA, uB;
        // u = max(shr1(c), a) for both chains; lanes 0/32 fixed below
        asm("s_nop 1\n\t"
            "v_max_f32_dpp %0, %2, %3 wave_shr:1 row_mask:0xf bank_mask:0xf\n\t"
            "v_max_f32_dpp %1, %4, %5 wave_shr:1 row_mask:0xf bank_mask:0xf"
            : "=&v"(uA), "=&v"(uB)
            : "v"(cA), "v"(aA), "v"(cB), "v"(aB));
        uA = l0c ? aA : uA;                     // lanes 0,32: u = a (own only)
        uB = l0c ? aB : uB;
        scan_max32_x2(uA, uB);                  // dual fused prefix max
        float vA = ZoA - uA;                    // S + prefmin(e)
        float vB = ZoB - uB;
        if (first && k4 == 0 && e == 0) {       // init col = cumsum = Z - KB
          vA = ZoA - KB;
          vB = ZoB - KB;
        }
        dcurA = vA; dcurB = vB;
        if (e == 0) { rvA.x = vA; rvB.x = vB; }
        else if (e == 1) { rvA.y = vA; rvB.y = vB; }
        else if (e == 2) { rvA.z = vA; rvB.z = vB; }
        else { rvA.w = vA; rvB.w = vB; }
      }
      if (k4 == 0) { rA0 = rvA; rB0 = rvB; }
      else if (k4 == 1) { rA1 = rvA; rB1 = rvB; }
      else if (k4 == 2) { rA2 = rvA; rB2 = rvB; }
      else { rA3 = rvA; rB3 = rvB; }
    }
    if (store) {                      // one exec-mask region per tile
      if (l31) {
        float* opA = orowA + (t << 4);
        float* opB = orowB + (t << 4);
        float4 s;
        s.x = __builtin_amdgcn_sqrtf(rA0.x); s.y = __builtin_amdgcn_sqrtf(rA0.y);
        s.z = __builtin_amdgcn_sqrtf(rA0.z); s.w = __builtin_amdgcn_sqrtf(rA0.w);
        *(float4*)(opA + 0) = s;
        s.x = __builtin_amdgcn_sqrtf(rA1.x); s.y = __builtin_amdgcn_sqrtf(rA1.y);
        s.z = __builtin_amdgcn_sqrtf(rA1.z); s.w = __builtin_amdgcn_sqrtf(rA1.w);
        *(float4*)(opA + 4) = s;
        s.x = __builtin_amdgcn_sqrtf(rA2.x); s.y = __builtin_amdgcn_sqrtf(rA2.y);
        s.z = __builtin_amdgcn_sqrtf(rA2.z); s.w = __builtin_amdgcn_sqrtf(rA2.w);
        *(float4*)(opA + 8) = s;
        s.x = __builtin_amdgcn_sqrtf(rA3.x); s.y = __builtin_amdgcn_sqrtf(rA3.y);
        s.z = __builtin_amdgcn_sqrtf(rA3.z); s.w = __builtin_amdgcn_sqrtf(rA3.w);
        *(float4*)(opA + 12) = s;
        s.x = __builtin_amdgcn_sqrtf(rB0.x); s.y = __builtin_amdgcn_sqrtf(rB0.y);
        s.z = __builtin_amdgcn_sqrtf(rB0.z); s.w = __builtin_amdgcn_sqrtf(rB0.w);
        *(float4*)(opB + 0) = s;
        s.x = __builtin_amdgcn_sqrtf(rB1.x); s.y = __builtin_amdgcn_sqrtf(rB1.y);
        s.z = __builtin_amdgcn_sqrtf(rB1.z); s.w = __builtin_amdgcn_sqrtf(rB1.w);
        *(float4*)(opB + 4) = s;
        s.x = __builtin_amdgcn_sqrtf(rB2.x); s.y = __builtin_amdgcn_sqrtf(rB2.y);
        s.z = __builtin_amdgcn_sqrtf(rB2.z); s.w = __builtin_amdgcn_sqrtf(rB2.w);
        *(float4*)(opB + 8) = s;
        s.x = __builtin_amdgcn_sqrtf(rB3.x); s.y = __builtin_amdgcn_sqrtf(rB3.y);
        s.z = __builtin_amdgcn_sqrtf(rB3.z); s.w = __builtin_amdgcn_sqrtf(rB3.w);
        *(float4*)(opB + 12) = s;
      }
    }
  }
}

extern "C" void kernel_launch(void* const* d_in, const int* in_sizes, int n_in,
                              void* d_out, int out_size, void* d_ws, size_t ws_size,
                              hipStream_t stream) {
  const float* x     = (const float*)d_in[0];
  const float* patts = (const float*)d_in[1];
  const float* w     = (const float*)d_in[2];
  float* out = (float*)d_out;

  ushort_t* xA = (ushort_t*)d_ws;                                       // 2 MiB
  ushort_t* pB = (ushort_t*)((char*)d_ws + (size_t)B_ * T_ * 32 * 2);   // 128 KiB

  prep_fused<<<144, 256, 0, stream>>>(x, patts, xA, pB);
  dtw_kernel<<<B_ * 4 * 8, 256, 0, stream>>>(xA, pB, w, out);
}

// Round 7
// 117.141 us; speedup vs baseline: 1.1688x; 1.1688x over previous
//
#include <hip/hip_runtime.h>
#include <math.h>

#define B_ 32
#define D_ 16
#define T_ 1024
#define P_ 64
#define L_ 32
#define BIGV 1.0e30f

typedef short short8 __attribute__((ext_vector_type(8)));
typedef float f32x4 __attribute__((ext_vector_type(4)));
typedef unsigned short ushort_t;

// ---- DPP helper ------------------------------------------------------------
template<int CTRL, int ROW_MASK, bool BC>
__device__ __forceinline__ float dpp_mov(float old_, float src) {
  int o = __builtin_bit_cast(int, old_);
  int s = __builtin_bit_cast(int, src);
  int r = __builtin_amdgcn_update_dpp(o, s, CTRL, ROW_MASK, 0xf, BC);
  return __builtin_bit_cast(float, r);
}

__device__ __forceinline__ ushort_t f2bf(float f) {   // fp32 -> bf16 RNE
  unsigned u = __builtin_bit_cast(unsigned, f);
  return (ushort_t)((u + 0x7FFFu + ((u >> 16) & 1u)) >> 16);
}
__device__ __forceinline__ float bf2f(ushort_t h) {
  unsigned u = ((unsigned)h) << 16;
  return __builtin_bit_cast(float, u);
}

// ---- fused prep: blocks 0..127 prep_x, blocks 128..143 prep_patt x4 --------
// R7: B fragments now hold RAW pattern data (no prefix scans): the diagonal
// DP consumes raw costs. S_mfma[i][j] = -2*sum_d x_d p_d[i] + p2[i] + x2[j].
// pB[p][iblk][lane][8]: k<16: -2*patt[d=k][i]; k=16/17: p2hi/lo(i);
// k=18/19: 1.0 (to pick up x2hi/lo from A); k>=20: 0.
__global__ __launch_bounds__(256) void prep_fused(
    const float* __restrict__ x, const float* __restrict__ patts,
    ushort_t* __restrict__ xA, ushort_t* __restrict__ pB) {
  const int bid = blockIdx.x;
  if (bid < 128) {
    int gid = bid * 256 + threadIdx.x;      // < 32768 = B_*T_
    int b = gid >> 10, t = gid & 1023;
    float x2 = 0.f;
    ushort_t o[32];
#pragma unroll
    for (int d = 0; d < 16; ++d) {
      float v = x[((b * 16 + d) << 10) + t];   // coalesced over t
      x2 = fmaf(v, v, x2);
      o[d] = f2bf(v);
    }
    o[16] = 0x3F80; o[17] = 0x3F80;            // bf16(1.0)
    ushort_t hi = f2bf(x2);
    o[18] = hi;
    o[19] = f2bf(x2 - bf2f(hi));               // hi/lo split
#pragma unroll
    for (int d = 20; d < 32; ++d) o[d] = 0;
    uint4* dst = (uint4*)(xA + (size_t)gid * 32);
#pragma unroll
    for (int q = 0; q < 4; ++q) {
      const ushort_t* s = o + q * 8;
      uint4 u;
      u.x = (unsigned)s[0] | ((unsigned)s[1] << 16);
      u.y = (unsigned)s[2] | ((unsigned)s[3] << 16);
      u.z = (unsigned)s[4] | ((unsigned)s[5] << 16);
      u.w = (unsigned)s[6] | ((unsigned)s[7] << 16);
      dst[q] = u;
    }
  } else {
    __shared__ float Ls[4][16 * 33];
    __shared__ float Lh[4][64];
    __shared__ float LP2[4][32];
    const int sub = threadIdx.x >> 6;
    const int l = threadIdx.x & 63;
    const int p = (bid - 128) * 4 + sub;
    const int half = l >> 5;
    const int m = l & 31;

    float p2acc = 0.f;
#pragma unroll
    for (int dd = 0; dd < 16; dd += 2) {
      int d = dd + half;                       // half 0: even d, half 1: odd d
      float v = patts[((p * 16 + d) << 5) + m];
      p2acc = fmaf(v, v, p2acc);
      Ls[sub][d * 33 + m] = v;                 // RAW value (no prefix)
    }
    Lh[sub][l] = p2acc;
    __syncthreads();
    {
      float tot = Lh[sub][m] + Lh[sub][32 + m];  // p2 of position m (raw)
      if (half == 0) LP2[sub][m] = tot;
    }
    __syncthreads();

    const int n = l & 15, q = l >> 4;
#pragma unroll
    for (int iblk = 0; iblk < 2; ++iblk) {
      const int i = iblk * 16 + n;
      ushort_t o[8];
      if (q < 2) {
#pragma unroll
        for (int e = 0; e < 8; ++e)
          o[e] = f2bf(-2.f * Ls[sub][(q * 8 + e) * 33 + i]);
      } else if (q == 2) {
        float P2 = LP2[sub][i];
        ushort_t hi = f2bf(P2);
        o[0] = hi; o[1] = f2bf(P2 - bf2f(hi));
        o[2] = 0x3F80; o[3] = 0x3F80;          // 1.0: picks up x2hi/lo
        o[4] = o[5] = o[6] = o[7] = 0;
      } else {
#pragma unroll
        for (int e = 0; e < 8; ++e) o[e] = 0;
      }
      uint4 u;
      u.x = (unsigned)o[0] | ((unsigned)o[1] << 16);
      u.y = (unsigned)o[2] | ((unsigned)o[3] << 16);
      u.z = (unsigned)o[4] | ((unsigned)o[5] << 16);
      u.w = (unsigned)o[6] | ((unsigned)o[7] << 16);
      ((uint4*)pB)[(p * 2 + iblk) * 64 + l] = u;
    }
  }
}

// ---- main kernel: ANTI-DIAGONAL wavefront DP -------------------------------
// R7: the per-column 32-lane prefix-max scan (43 VALU-cyc issue, 290-cyc
// latency per column — the measured R1-R6 wall) is ELIMINATED. On diagonal
// d, cell (i, j=d-i) needs only diag d-1 (shifted=up, unshifted=left) and
// d-2 (shifted=diag); the shifted d-2 term is last step's shift (register
// reuse). Per step: 1 dpp_mov + cndmask + fmin + fmul + fmin + fadd = 6 VALU,
// chain ~25 cyc. Costs are RAW (prep change), read diagonally from a 3-tile
// (48-col) LDS ring, stride 50 (conflict <=2-way = free; 8B-aligned writes).
// All 16 c-reads per 16-step iteration batched at iteration top (one lgkm
// cluster). Prologue = 31 diagonals with j<0 masking (BIGV); d=0 seeds the
// cumsum. Exact reference min-order per cell.
// Geometry: C=4 chunks (R3's, uniform 28 tiles, 16-tile warm), 4-wave blocks,
// grid 1024; LDS 51200 B/block -> 3 blocks/CU.
__global__ __launch_bounds__(256, 3) void dtw_kernel(
    const ushort_t* __restrict__ xA,    // [B][T][32 bf16]
    const ushort_t* __restrict__ pBg,   // [P][2][64][8 bf16]
    const float* __restrict__ wp,
    float* __restrict__ out)            // [B][P][T]
{
  __shared__ float lds[4 * 3200];   // 4 waves * 2 patterns * 32 rows * 50

  const int tid = threadIdx.x;
  const int l   = tid & 63;
  const int wid = tid >> 6;
  const int li  = l & 31;
  const int g   = l >> 5;
  const int q4  = l >> 4;
  const unsigned bx = blockIdx.x;
  const int ch   = bx & 3u;
  const unsigned rest = bx >> 2;
  const int b     = rest >> 3;
  const int pbase = (rest & 7) << 3;
  const int pA  = pbase + (wid << 1);
  const float w = wp[0];
  const bool l0c = (li == 0);

  const int S0    = 12 * ch;            // start tile (R3 chunking)
  const int warmU = ch ? 16 : 0;        // col-tiles not stored

  // B fragments (loop-invariant MFMA operands)
  const short8* pBs = (const short8*)pBg;
  short8 B00 = pBs[((pA    ) * 2 + 0) * 64 + l];
  short8 B01 = pBs[((pA    ) * 2 + 1) * 64 + l];
  short8 B10 = pBs[((pA + 1) * 2 + 0) * 64 + l];
  short8 B11 = pBs[((pA + 1) * 2 + 1) * 64 + l];

  const short8* xAs = (const short8*)xA + ((size_t)b << 12);
  short8 Aa;
  auto loadA = [&](int t) {
    Aa = xAs[((((S0 + t) << 4) + (l & 15)) << 2) + q4];
  };

  float* wbase = lds + wid * 3200;
  const f32x4 zk = {0.f, 0.f, 0.f, 0.f};

  // fill tile into ring slot rs (cols rs*16..rs*16+15 of the 48-col ring)
  auto fill = [&](int rs) {
    float* wb = wbase + (l & 15) * 50 + rs * 16 + q4 * 4;
    f32x4 d0 = __builtin_amdgcn_mfma_f32_16x16x32_bf16(Aa, B00, zk, 0, 0, 0);
    f32x4 d1 = __builtin_amdgcn_mfma_f32_16x16x32_bf16(Aa, B01, zk, 0, 0, 0);
    f32x4 d2 = __builtin_amdgcn_mfma_f32_16x16x32_bf16(Aa, B10, zk, 0, 0, 0);
    f32x4 d3 = __builtin_amdgcn_mfma_f32_16x16x32_bf16(Aa, B11, zk, 0, 0, 0);
    float2 t2;
    // pat0 rows 0..15 (stride-50 rows; 8B-aligned b64 writes)
    t2.x = d0[0]; t2.y = d0[1]; *(float2*)(wb + 0) = t2;
    t2.x = d0[2]; t2.y = d0[3]; *(float2*)(wb + 2) = t2;
    // pat0 rows 16..31
    t2.x = d1[0]; t2.y = d1[1]; *(float2*)(wb + 800) = t2;
    t2.x = d1[2]; t2.y = d1[3]; *(float2*)(wb + 802) = t2;
    // pat1 rows 0..15
    t2.x = d2[0]; t2.y = d2[1]; *(float2*)(wb + 1600) = t2;
    t2.x = d2[2]; t2.y = d2[3]; *(float2*)(wb + 1602) = t2;
    // pat1 rows 16..31
    t2.x = d3[0]; t2.y = d3[1]; *(float2*)(wb + 2400) = t2;
    t2.x = d3[2]; t2.y = d3[3]; *(float2*)(wb + 2402) = t2;
  };

  // per-lane cost-row base; ring byte offset offb = ((j mod 48) << 2)
  const char* crow = (const char*)(wbase + g * 1600 + li * 50);

  float* orow = out + (((size_t)(b * P_ + pA + g)) << 10) + (S0 << 4);

  loadA(0); fill(0);
  loadA(1); fill(1);
  loadA(2);

  // ---- prologue: diagonals d = 0..30 (j = d - li; j<0 lanes -> BIGV) ----
  float prev, sp2 = BIGV;
  int offb = ((li == 0) ? 0 : (48 - li)) << 2;   // (0 - li) mod 48, bytes
  {
    float c0 = *(const float*)(crow + offb);
    prev = l0c ? c0 : BIGV;                      // D(0, t0) = cost; rest OOR
    offb += 4; if (offb >= 192) offb -= 192;
  }
  for (int d = 1; d < 31; ++d) {
    float c = *(const float*)(crow + offb);
    offb += 4; if (offb >= 192) offb -= 192;
    float sp = dpp_mov<0x138, 0xf, true>(0.f, prev);  // up = D[i-1] (shr1)
    sp = l0c ? BIGV : sp;                             // lanes 0,32: no i-1
    float u2 = fminf(prev, sp2);                      // min(left, diag)
    float r  = fminf(sp, w * u2);
    float Dv = c + r;
    Dv = (li > d) ? BIGV : Dv;                        // j < 0 -> boundary
    sp2 = sp; prev = Dv;
  }

  // ---- main: 28 iterations x 16 diagonals (d = 31+16u+s; j31 = 16u+s) ----
  int rsf = 2;                                   // ring slot of next fill
  for (int u = 0; u < 28; ++u) {
    if (u + 2 < 28) {
      fill(rsf);                                 // tile u+2 (uses Aa)
      rsf = (rsf == 2) ? 0 : rsf + 1;
    }
    if (u + 3 < 28) loadA(u + 3);

    // batch the 16 diagonal c-reads (one lgkm cluster; ring-48 wrap)
    float cv[16];
#pragma unroll
    for (int s = 0; s < 16; ++s) {
      int ob = offb + 4 * s;
      ob = (ob >= 192) ? ob - 192 : ob;
      cv[s] = *(const float*)(crow + ob);
    }
    offb += 64; if (offb >= 192) offb -= 192;

    float Ds[16];
#pragma unroll
    for (int s = 0; s < 16; ++s) {
      float sp = dpp_mov<0x138, 0xf, true>(0.f, prev);
      sp = l0c ? BIGV : sp;
      float u2 = fminf(prev, sp2);
      float r  = fminf(sp, w * u2);
      float Dv = cv[s] + r;
      sp2 = sp; prev = Dv;
      Ds[s] = Dv;
    }

    if (u >= warmU) {
      if (li == 31) {                            // lane 31 / 63 hold D[L-1]
        float* op = orow + (u << 4);
        float4 s4;
        s4.x = __builtin_amdgcn_sqrtf(fmaxf(Ds[0], 0.f));
        s4.y = __builtin_amdgcn_sqrtf(fmaxf(Ds[1], 0.f));
        s4.z = __builtin_amdgcn_sqrtf(fmaxf(Ds[2], 0.f));
        s4.w = __builtin_amdgcn_sqrtf(fmaxf(Ds[3], 0.f));
        *(float4*)(op + 0) = s4;
        s4.x = __builtin_amdgcn_sqrtf(fmaxf(Ds[4], 0.f));
        s4.y = __builtin_amdgcn_sqrtf(fmaxf(Ds[5], 0.f));
        s4.z = __builtin_amdgcn_sqrtf(fmaxf(Ds[6], 0.f));
        s4.w = __builtin_amdgcn_sqrtf(fmaxf(Ds[7], 0.f));
        *(float4*)(op + 4) = s4;
        s4.x = __builtin_amdgcn_sqrtf(fmaxf(Ds[8], 0.f));
        s4.y = __builtin_amdgcn_sqrtf(fmaxf(Ds[9], 0.f));
        s4.z = __builtin_amdgcn_sqrtf(fmaxf(Ds[10], 0.f));
        s4.w = __builtin_amdgcn_sqrtf(fmaxf(Ds[11], 0.f));
        *(float4*)(op + 8) = s4;
        s4.x = __builtin_amdgcn_sqrtf(fmaxf(Ds[12], 0.f));
        s4.y = __builtin_amdgcn_sqrtf(fmaxf(Ds[13], 0.f));
        s4.z = __builtin_amdgcn_sqrtf(fmaxf(Ds[14], 0.f));
        s4.w = __builtin_amdgcn_sqrtf(fmaxf(Ds[15], 0.f));
        *(float4*)(op + 12) = s4;
      }
    }
  }
}

extern "C" void kernel_launch(void* const* d_in, const int* in_sizes, int n_in,
                              void* d_out, int out_size, void* d_ws, size_t ws_size,
                              hipStream_t stream) {
  const float* x     = (const float*)d_in[0];
  const float* patts = (const float*)d_in[1];
  const float* w     = (const float*)d_in[2];
  float* out = (float*)d_out;

  ushort_t* xA = (ushort_t*)d_ws;                                       // 2 MiB
  ushort_t* pB = (ushort_t*)((char*)d_ws + (size_t)B_ * T_ * 32 * 2);   // 128 KiB

  prep_fused<<<144, 256, 0, stream>>>(x, patts, xA, pB);
  dtw_kernel<<<B_ * 8 * 4, 256, 0, stream>>>(xA, pB, w, out);
}